// Round 17
// baseline (122.943 us; speedup 1.0000x reference)
//
#include <hip/hip_runtime.h>

// Problem constants
constexpr int Bn   = 8;
constexpr int Nn   = 1024;
constexpr int DIMn = 768;       // K for both GEMMs
constexpr int Hn   = 12;
constexpr int HDn  = 64;
constexpr int INNERn = Hn * HDn;     // 768
constexpr int QKVCOLS = 3 * INNERn;  // 2304
constexpr int Mrows = Bn * Nn;       // 8192
// q scale with log2(e) folded: softmax uses exp2
constexpr float QSCL = 0.18033688011112042f;   // 0.125 * log2(e)

typedef float f32x4 __attribute__((ext_vector_type(4)));
typedef __bf16 bf16x8 __attribute__((ext_vector_type(8)));
typedef __bf16 bf16x4 __attribute__((ext_vector_type(4)));

static __device__ __forceinline__ float fexp2(float x) {
#if __has_builtin(__builtin_amdgcn_exp2f)
    return __builtin_amdgcn_exp2f(x);
#else
    return exp2f(x);
#endif
}

// async global->LDS, 16B per lane; LDS dest = wave-uniform base + lane*16
static __device__ __forceinline__ void gload16(const void* g, void* l) {
    __builtin_amdgcn_global_load_lds(
        (const __attribute__((address_space(1))) unsigned int*)g,
        (__attribute__((address_space(3))) unsigned int*)l, 16, 0, 0);
}

// ---------------------------------------------------------------------------
// prep: fused (a) transpose wqkv -> wqkvT bf16, (b) transpose wout -> woutT,
// (c) head_scale. One dispatch.
// ---------------------------------------------------------------------------
__global__ __launch_bounds__(256) void prep_kernel(
    const float* __restrict__ wqkv, const float* __restrict__ wout,
    const float* __restrict__ rw,
    __bf16* __restrict__ wqkvT, __bf16* __restrict__ woutT,
    float* __restrict__ hs)
{
    __shared__ float Ls[64][68];
    __shared__ float red[256];
    const int bx = blockIdx.x;
    const int t = threadIdx.x;

    if (bx >= 48) {
        if (blockIdx.y != 0) return;
        int h = bx - 48;
        const float* p = rw + (size_t)h * (HDn * HDn);
        float s = 0.f;
        for (int i = t; i < HDn * HDn; i += 256) s += p[i];
        red[t] = s;
        __syncthreads();
        #pragma unroll
        for (int off = 128; off > 0; off >>= 1) {
            if (t < off) red[t] += red[t + off];
            __syncthreads();
        }
        if (t == 0) hs[h] = red[0];
        return;
    }

    const float* w;  __bf16* wT;  int N, n0;
    if (bx < 36) { w = wqkv; wT = wqkvT; N = QKVCOLS; n0 = bx * 64; }
    else         { w = wout; wT = woutT; N = INNERn;  n0 = (bx - 36) * 64; }
    int k0 = blockIdx.y * 64;
    int cc = t & 15, rr = t >> 4;
    #pragma unroll
    for (int it = 0; it < 4; ++it) {
        int row = rr + it * 16;
        float4 v = *(const float4*)(w + (size_t)(k0 + row) * N + n0 + cc * 4);
        *(float4*)(&Ls[row][cc * 4]) = v;
    }
    __syncthreads();
    #pragma unroll
    for (int it = 0; it < 4; ++it) {
        int nr = rr + it * 16;
        bf16x4 o;
        #pragma unroll
        for (int i = 0; i < 4; ++i) o[i] = (__bf16)Ls[cc * 4 + i][nr];
        *(bf16x4*)(wT + (size_t)(n0 + nr) * 768 + k0 + cc * 4) = o;
    }
}

// ---------------------------------------------------------------------------
// bf16 MFMA GEMM, 128x128 tile, BK=64, 4 waves (2x2 of 64x64), K=768,
// SINGLE-buffered (best measured structure).
// AF32=1: A fp32 (x read directly, cvt to bf16 at frag-read).
// 1D grid, XCD-aware: bid = nt*64 + mt (same-mt -> same XCD). [T1]
// EPI 0: +bias; q scaled by QSCL -> qb; k -> kb;
//        v -> vt TRANSPOSED, j-PERMUTED inside each 64-tile:
//        u = j&63 -> p = (u&32) + ((u&15)>>2)*8 + ((u>>4)&1)*4 + (u&3)
//        so attn's PV B-fragment is one contiguous b128 LDS read.
// EPI 1: +bias, fp32 out row-major.
// ---------------------------------------------------------------------------
template<int EPI, int AF32>
__global__ __launch_bounds__(256) void gemm_bf16_kernel(
    const void* __restrict__ Ap, const __bf16* __restrict__ BT,
    const float* __restrict__ bias,
    __bf16* __restrict__ qb, __bf16* __restrict__ kb, __bf16* __restrict__ vt,
    float* __restrict__ outp)
{
    constexpr int K = 768;
    __shared__ __attribute__((aligned(16))) char AsRaw[AF32 ? 32768 : 16384];
    __shared__ __attribute__((aligned(16))) __bf16 Bs[128][64];

    const float*  A32 = (const float*)Ap;
    const __bf16* A16 = (const __bf16*)Ap;
    float*  As32 = (float*)AsRaw;
    __bf16* As16 = (__bf16*)AsRaw;

    const int tid = threadIdx.x;
    const int lane = tid & 63, w = tid >> 6;
    const int g = lane >> 4, l16 = lane & 15;
    const int wm = (w >> 1) * 64, wn = (w & 1) * 64;
    const int bid = blockIdx.x;
    const int m0 = (bid & 63) * 128;       // mt = bid % 64 (same-mt -> same XCD)
    const int n0 = (bid >> 6) * 128;       // nt

    f32x4 acc[4][4] = {};

    for (int kt = 0; kt < K; kt += 64) {
        __syncthreads();   // previous iteration's readers done
        if (AF32) {
            int lr = lane >> 4, sl = lane & 15;
            #pragma unroll
            for (int i = 0; i < 8; ++i) {
                int rbase = w * 32 + i * 4;
                int row = rbase + lr;
                gload16(A32 + (size_t)(m0 + row) * K + kt + ((sl ^ (row & 15)) << 2),
                        As32 + rbase * 64);
            }
        } else {
            int lr = lane >> 3, sl = lane & 7;
            #pragma unroll
            for (int i = 0; i < 4; ++i) {
                int rbase = w * 32 + i * 8;
                int row = rbase + lr;
                gload16(A16 + (size_t)(m0 + row) * K + kt + ((sl ^ (row & 7)) << 3),
                        As16 + rbase * 64);
            }
        }
        {
            int lr = lane >> 3, sl = lane & 7;
            #pragma unroll
            for (int i = 0; i < 4; ++i) {
                int rbase = w * 32 + i * 8;
                int row = rbase + lr;
                gload16(BT + (size_t)(n0 + row) * K + kt + ((sl ^ (row & 7)) << 3),
                        &Bs[rbase][0]);
            }
        }
        __syncthreads();   // drains vmcnt -> LDS ready

        #pragma unroll
        for (int s = 0; s < 2; ++s) {
            bf16x8 af[4], bfr[4];
            #pragma unroll
            for (int f = 0; f < 4; ++f) {
                int ar = wm + f * 16 + l16;
                if (AF32) {
                    const float* base = As32 + ar * 64;
                    f32x4 va0 = *(const f32x4*)(base + (((s * 8 + g * 2 + 0) ^ l16) << 2));
                    f32x4 va1 = *(const f32x4*)(base + (((s * 8 + g * 2 + 1) ^ l16) << 2));
                    af[f] = bf16x8{ (__bf16)va0[0], (__bf16)va0[1], (__bf16)va0[2], (__bf16)va0[3],
                                    (__bf16)va1[0], (__bf16)va1[1], (__bf16)va1[2], (__bf16)va1[3] };
                } else {
                    af[f] = *(const bf16x8*)(As16 + ar * 64 + ((s * 4 + g) ^ (ar & 7)) * 8);
                }
                int br = wn + f * 16 + l16;
                bfr[f] = *(const bf16x8*)(&Bs[br][((s * 4 + g) ^ (br & 7)) * 8]);
            }
            #pragma unroll
            for (int fa = 0; fa < 4; ++fa)
                #pragma unroll
                for (int fb = 0; fb < 4; ++fb)
                    acc[fa][fb] = __builtin_amdgcn_mfma_f32_16x16x32_bf16(
                        af[fa], bfr[fb], acc[fa][fb], 0, 0, 0);
        }
    }

    // epilogue: C/D layout col = lane&15, row = g*4 + reg
    #pragma unroll
    for (int fa = 0; fa < 4; ++fa) {
        #pragma unroll
        for (int fb = 0; fb < 4; ++fb) {
            int n = n0 + wn + fb * 16 + l16;
            float bn = bias[n];
            float v0 = acc[fa][fb][0] + bn;
            float v1 = acc[fa][fb][1] + bn;
            float v2 = acc[fa][fb][2] + bn;
            float v3 = acc[fa][fb][3] + bn;
            int mbase = m0 + wm + fa * 16 + g * 4;   // 4 consecutive rows
            if (EPI == 0) {
                int which = n / INNERn;
                int rem = n - which * INNERn;
                int hh = rem >> 6, d = rem & 63;
                int bb = mbase >> 10;                // tile never straddles b
                int nn = mbase & 1023;
                size_t bh = (size_t)bb * Hn + hh;
                if (which == 2) {
                    // V^T with intra-64 j-permutation (see header comment)
                    int nn0 = nn & ~63;
                    int u = nn & 63;
                    int p = (u & 32) + (((u & 15) >> 2) << 3) + (((u >> 4) & 1) << 2);
                    bf16x4 o = { (__bf16)v0, (__bf16)v1, (__bf16)v2, (__bf16)v3 };
                    *(bf16x4*)(vt + (bh * 64 + d) * Nn + nn0 + p) = o;
                } else {
                    float sc = (which == 0) ? QSCL : 1.0f;
                    __bf16* dst = (which == 0) ? qb : kb;
                    size_t base = ((bh * Nn + nn) << 6) + d;
                    dst[base]       = (__bf16)(v0 * sc);
                    dst[base + 64]  = (__bf16)(v1 * sc);
                    dst[base + 128] = (__bf16)(v2 * sc);
                    dst[base + 192] = (__bf16)(v3 * sc);
                }
            } else {
                outp[(size_t)(mbase + 0) * INNERn + n] = v0;
                outp[(size_t)(mbase + 1) * INNERn + n] = v1;
                outp[(size_t)(mbase + 2) * INNERn + n] = v2;
                outp[(size_t)(mbase + 3) * INNERn + n] = v3;
            }
        }
    }
}

// ---------------------------------------------------------------------------
// Fused attention. 4 waves, 2 q-tiles per block. 2-phase LDS pipeline,
// STATIC softmax (exp2, log2e pre-folded into Q). l via MFMA-with-ones.
// V stored j-permuted -> single b128 V-read.
// T5 setprio(1) around both MFMA clusters (blocks at staggered phases
// co-resident -> m191 attn regime); stage-issue split: K-stage before QK^T,
// V-stage after (spreads VMEM issue under compute).
// 1D grid, XCD-aware: bid = qt*96 + bh (same-bh -> same XCD). [T1]
// ---------------------------------------------------------------------------
__global__ __launch_bounds__(256) void attn_mfma_kernel(
    const __bf16* __restrict__ qb, const __bf16* __restrict__ kb,
    const __bf16* __restrict__ vT, const float* __restrict__ hs,
    __bf16* __restrict__ ao)
{
    __shared__ __attribute__((aligned(16))) __bf16 Ks[2][64][64];
    __shared__ __attribute__((aligned(16))) __bf16 Vs[2][64][64];

    const int tid = threadIdx.x;
    const int lane = tid & 63, w = tid >> 6;
    const int g = lane >> 4, l16 = lane & 15;
    const int bid = blockIdx.x;
    const int bh = bid % 96;            // same bh -> same XCD (96 === 0 mod 8)
    const int qt = bid / 96;            // 0..7
    const int b = bh / Hn, h = bh - b * Hn;

    const __bf16* Qp = qb + ((size_t)bh * Nn + qt * 128 + w * 16) * 64;
    const __bf16* Kp = kb + (size_t)bh * Nn * 64;
    const __bf16* Vp = vT + (size_t)bh * 64 * Nn;

    const int srl = lane >> 3;   // 0..7 local row
    const int ssl = lane & 7;    // chunk slot 0..7

    const __bf16 one1 = (__bf16)1.0f;
    const bf16x8 vones = { one1, one1, one1, one1, one1, one1, one1, one1 };

    bf16x8 qf[2][2];
    #pragma unroll
    for (int t = 0; t < 2; ++t)
        #pragma unroll
        for (int s = 0; s < 2; ++s)
            qf[t][s] = *(const bf16x8*)(Qp + t * 64 * 64 + (size_t)l16 * 64 + s * 32 + g * 8);

    f32x4 oacc0[4] = {}, oacc1[4] = {};
    f32x4 lacc0 = {}, lacc1 = {};

    #pragma unroll
    for (int i = 0; i < 2; ++i) {
        int row = w * 16 + i * 8 + srl;
        gload16(Kp + (size_t)row * 64 + ((ssl ^ (row & 7)) << 3),
                &Ks[0][w * 16 + i * 8][0]);
        gload16(Vp + (size_t)row * Nn + ((ssl ^ (row & 7)) << 3),
                &Vs[0][w * 16 + i * 8][0]);
    }
    __syncthreads();

    int cur = 0;
    for (int jt = 0; jt < Nn / 64; ++jt) {
        const bool pre = (jt < Nn / 64 - 1);
        const __bf16* kbase = Kp + (size_t)(jt + 1) * 64 * 64;
        const __bf16* vbase = Vp + (size_t)(jt + 1) * 64;

        // ---- issue NEXT K-stage (in flight over QK^T) ----
        if (pre) {
            #pragma unroll
            for (int i = 0; i < 2; ++i) {
                int row = w * 16 + i * 8 + srl;
                gload16(kbase + (size_t)row * 64 + ((ssl ^ (row & 7)) << 3),
                        &Ks[cur ^ 1][w * 16 + i * 8][0]);
            }
        }

        // ---- S^T for both q-tiles ----
        f32x4 st0[4] = {}, st1[4] = {};
        __builtin_amdgcn_s_setprio(1);
        #pragma unroll
        for (int s = 0; s < 2; ++s) {
            #pragma unroll
            for (int jf = 0; jf < 4; ++jf) {
                bf16x8 kf = *(const bf16x8*)(
                    &Ks[cur][jf * 16 + l16][((s * 4 + g) ^ (l16 & 7)) * 8]);
                st0[jf] = __builtin_amdgcn_mfma_f32_16x16x32_bf16(kf, qf[0][s], st0[jf], 0, 0, 0);
                st1[jf] = __builtin_amdgcn_mfma_f32_16x16x32_bf16(kf, qf[1][s], st1[jf], 0, 0, 0);
            }
        }
        __builtin_amdgcn_s_setprio(0);

        // ---- issue NEXT V-stage (in flight over softmax + PV) ----
        if (pre) {
            #pragma unroll
            for (int i = 0; i < 2; ++i) {
                int row = w * 16 + i * 8 + srl;
                gload16(vbase + (size_t)row * Nn + ((ssl ^ (row & 7)) << 3),
                        &Vs[cur ^ 1][w * 16 + i * 8][0]);
            }
        }

        // ---- static softmax: P = exp2(S') ----
        #pragma unroll
        for (int f = 0; f < 4; ++f)
            #pragma unroll
            for (int r = 0; r < 4; ++r) {
                st0[f][r] = fexp2(st0[f][r]);
                st1[f][r] = fexp2(st1[f][r]);
            }

        // ---- pack P into A-operand fragments ----
        bf16x8 pa0[2], pa1[2];
        #pragma unroll
        for (int s = 0; s < 2; ++s) {
            pa0[s] = bf16x8{ (__bf16)st0[2*s][0], (__bf16)st0[2*s][1],
                             (__bf16)st0[2*s][2], (__bf16)st0[2*s][3],
                             (__bf16)st0[2*s+1][0], (__bf16)st0[2*s+1][1],
                             (__bf16)st0[2*s+1][2], (__bf16)st0[2*s+1][3] };
            pa1[s] = bf16x8{ (__bf16)st1[2*s][0], (__bf16)st1[2*s][1],
                             (__bf16)st1[2*s][2], (__bf16)st1[2*s][3],
                             (__bf16)st1[2*s+1][0], (__bf16)st1[2*s+1][1],
                             (__bf16)st1[2*s+1][2], (__bf16)st1[2*s+1][3] };
        }

        // ---- O += P @ V ; l += P @ ones ----
        __builtin_amdgcn_s_setprio(1);
        #pragma unroll
        for (int s = 0; s < 2; ++s) {
            lacc0 = __builtin_amdgcn_mfma_f32_16x16x32_bf16(pa0[s], vones, lacc0, 0, 0, 0);
            lacc1 = __builtin_amdgcn_mfma_f32_16x16x32_bf16(pa1[s], vones, lacc1, 0, 0, 0);
            #pragma unroll
            for (int df = 0; df < 4; ++df) {
                bf16x8 bv = *(const bf16x8*)(
                    &Vs[cur][df * 16 + l16][((s * 4 + g) ^ (l16 & 7)) * 8]);
                oacc0[df] = __builtin_amdgcn_mfma_f32_16x16x32_bf16(pa0[s], bv, oacc0[df], 0, 0, 0);
                oacc1[df] = __builtin_amdgcn_mfma_f32_16x16x32_bf16(pa1[s], bv, oacc1[df], 0, 0, 0);
            }
        }
        __builtin_amdgcn_s_setprio(0);

        __syncthreads();
        cur ^= 1;
    }

    // ---- epilogue: linv per row directly from lacc (no shuffles) ----
    const float hscale = hs[h];
    #pragma unroll
    for (int reg = 0; reg < 4; ++reg) {
        float li0 = hscale / lacc0[reg];
        float li1 = hscale / lacc1[reg];
        int q0 = qt * 128 + w * 16 + g * 4 + reg;
        #pragma unroll
        for (int df = 0; df < 4; ++df) {
            ao[((size_t)b * Nn + q0) * INNERn + h * 64 + df * 16 + l16] =
                (__bf16)(oacc0[df][reg] * li0);
            ao[((size_t)b * Nn + q0 + 64) * INNERn + h * 64 + df * 16 + l16] =
                (__bf16)(oacc1[df][reg] * li1);
        }
    }
}

// ---------------------------------------------------------------------------
extern "C" void kernel_launch(void* const* d_in, const int* in_sizes, int n_in,
                              void* d_out, int out_size, void* d_ws, size_t ws_size,
                              hipStream_t stream)
{
    const float* x    = (const float*)d_in[0];
    const float* wqkv = (const float*)d_in[1];
    const float* bqkv = (const float*)d_in[2];
    const float* rw   = (const float*)d_in[3];
    const float* wout = (const float*)d_in[4];
    const float* bout = (const float*)d_in[5];
    float* out = (float*)d_out;
    (void)in_sizes; (void)n_in; (void)out_size; (void)ws_size;

    char* ws = (char*)d_ws;
    size_t off = 0;
    auto alloc = [&](size_t bytes) -> char* {
        char* p = ws + off; off += (bytes + 255) & ~(size_t)255; return p;
    };
    const size_t tsz = (size_t)Mrows * INNERn;          // 6.29M elems
    float*  hsb   = (float*) alloc(Hn * 4);
    __bf16* wqkvT = (__bf16*)alloc((size_t)QKVCOLS * DIMn * 2);
    __bf16* woutT = (__bf16*)alloc((size_t)INNERn * DIMn * 2);
    __bf16* qbuf  = (__bf16*)alloc(tsz * 2);
    __bf16* kbuf  = (__bf16*)alloc(tsz * 2);
    __bf16* vTb   = (__bf16*)alloc(tsz * 2);
    __bf16* aob   = (__bf16*)alloc(tsz * 2);

    prep_kernel<<<dim3(60, 12), dim3(256), 0, stream>>>(
        wqkv, wout, rw, wqkvT, woutT, hsb);

    gemm_bf16_kernel<0, 1><<<dim3((QKVCOLS / 128) * (Mrows / 128)), dim3(256), 0, stream>>>(
        x, wqkvT, bqkv, qbuf, kbuf, vTb, nullptr);

    attn_mfma_kernel<<<dim3((Nn / 128) * Bn * Hn), dim3(256), 0, stream>>>(
        qbuf, kbuf, vTb, hsb, aob);

    gemm_bf16_kernel<1, 0><<<dim3((INNERn / 128) * (Mrows / 128)), dim3(256), 0, stream>>>(
        aob, woutT, bout, nullptr, nullptr, nullptr, out);
}

// Round 18
// 112.017 us; speedup vs baseline: 1.0975x; 1.0975x over previous
//
#include <hip/hip_runtime.h>

// Problem constants
constexpr int Bn   = 8;
constexpr int Nn   = 1024;
constexpr int DIMn = 768;       // K for both GEMMs
constexpr int Hn   = 12;
constexpr int HDn  = 64;
constexpr int INNERn = Hn * HDn;     // 768
constexpr int QKVCOLS = 3 * INNERn;  // 2304
constexpr int Mrows = Bn * Nn;       // 8192
// q scale with log2(e) folded: softmax uses exp2
constexpr float QSCL = 0.18033688011112042f;   // 0.125 * log2(e)

typedef float f32x4 __attribute__((ext_vector_type(4)));
typedef __bf16 bf16x8 __attribute__((ext_vector_type(8)));
typedef __bf16 bf16x4 __attribute__((ext_vector_type(4)));

static __device__ __forceinline__ float fexp2(float x) {
#if __has_builtin(__builtin_amdgcn_exp2f)
    return __builtin_amdgcn_exp2f(x);
#else
    return exp2f(x);
#endif
}

// async global->LDS, 16B per lane; LDS dest = wave-uniform base + lane*16
static __device__ __forceinline__ void gload16(const void* g, void* l) {
    __builtin_amdgcn_global_load_lds(
        (const __attribute__((address_space(1))) unsigned int*)g,
        (__attribute__((address_space(3))) unsigned int*)l, 16, 0, 0);
}

// ---------------------------------------------------------------------------
// prep: fused (a) transpose wqkv -> wqkvT bf16, (b) transpose wout -> woutT,
// (c) head_scale. One dispatch.
// ---------------------------------------------------------------------------
__global__ __launch_bounds__(256) void prep_kernel(
    const float* __restrict__ wqkv, const float* __restrict__ wout,
    const float* __restrict__ rw,
    __bf16* __restrict__ wqkvT, __bf16* __restrict__ woutT,
    float* __restrict__ hs)
{
    __shared__ float Ls[64][68];
    __shared__ float red[256];
    const int bx = blockIdx.x;
    const int t = threadIdx.x;

    if (bx >= 48) {
        if (blockIdx.y != 0) return;
        int h = bx - 48;
        const float* p = rw + (size_t)h * (HDn * HDn);
        float s = 0.f;
        for (int i = t; i < HDn * HDn; i += 256) s += p[i];
        red[t] = s;
        __syncthreads();
        #pragma unroll
        for (int off = 128; off > 0; off >>= 1) {
            if (t < off) red[t] += red[t + off];
            __syncthreads();
        }
        if (t == 0) hs[h] = red[0];
        return;
    }

    const float* w;  __bf16* wT;  int N, n0;
    if (bx < 36) { w = wqkv; wT = wqkvT; N = QKVCOLS; n0 = bx * 64; }
    else         { w = wout; wT = woutT; N = INNERn;  n0 = (bx - 36) * 64; }
    int k0 = blockIdx.y * 64;
    int cc = t & 15, rr = t >> 4;
    #pragma unroll
    for (int it = 0; it < 4; ++it) {
        int row = rr + it * 16;
        float4 v = *(const float4*)(w + (size_t)(k0 + row) * N + n0 + cc * 4);
        *(float4*)(&Ls[row][cc * 4]) = v;
    }
    __syncthreads();
    #pragma unroll
    for (int it = 0; it < 4; ++it) {
        int nr = rr + it * 16;
        bf16x4 o;
        #pragma unroll
        for (int i = 0; i < 4; ++i) o[i] = (__bf16)Ls[cc * 4 + i][nr];
        *(bf16x4*)(wT + (size_t)(n0 + nr) * 768 + k0 + cc * 4) = o;
    }
}

// ---------------------------------------------------------------------------
// bf16 MFMA GEMM, 128x128 tile, BK=64, 4 waves (2x2 of 64x64), K=768,
// SINGLE-buffered (best measured structure).
// AF32=1: A fp32 (x read directly, cvt to bf16 at frag-read).
// 1D grid, XCD-aware: bid = nt*64 + mt (same-mt -> same XCD). [T1]
// EPI 0: +bias; q scaled by QSCL -> qb; k -> kb;
//        v -> vt TRANSPOSED, j-PERMUTED inside each 64-tile:
//        u = j&63 -> p = (u&32) + ((u&15)>>2)*8 + ((u>>4)&1)*4 + (u&3)
//        so attn's PV B-fragment is one contiguous b128 LDS read.
// EPI 1: +bias, fp32 out row-major.
// ---------------------------------------------------------------------------
template<int EPI, int AF32>
__global__ __launch_bounds__(256) void gemm_bf16_kernel(
    const void* __restrict__ Ap, const __bf16* __restrict__ BT,
    const float* __restrict__ bias,
    __bf16* __restrict__ qb, __bf16* __restrict__ kb, __bf16* __restrict__ vt,
    float* __restrict__ outp)
{
    constexpr int K = 768;
    __shared__ __attribute__((aligned(16))) char AsRaw[AF32 ? 32768 : 16384];
    __shared__ __attribute__((aligned(16))) __bf16 Bs[128][64];

    const float*  A32 = (const float*)Ap;
    const __bf16* A16 = (const __bf16*)Ap;
    float*  As32 = (float*)AsRaw;
    __bf16* As16 = (__bf16*)AsRaw;

    const int tid = threadIdx.x;
    const int lane = tid & 63, w = tid >> 6;
    const int g = lane >> 4, l16 = lane & 15;
    const int wm = (w >> 1) * 64, wn = (w & 1) * 64;
    const int bid = blockIdx.x;
    const int m0 = (bid & 63) * 128;       // mt = bid % 64 (same-mt -> same XCD)
    const int n0 = (bid >> 6) * 128;       // nt

    f32x4 acc[4][4] = {};

    for (int kt = 0; kt < K; kt += 64) {
        __syncthreads();   // previous iteration's readers done
        if (AF32) {
            int lr = lane >> 4, sl = lane & 15;
            #pragma unroll
            for (int i = 0; i < 8; ++i) {
                int rbase = w * 32 + i * 4;
                int row = rbase + lr;
                gload16(A32 + (size_t)(m0 + row) * K + kt + ((sl ^ (row & 15)) << 2),
                        As32 + rbase * 64);
            }
        } else {
            int lr = lane >> 3, sl = lane & 7;
            #pragma unroll
            for (int i = 0; i < 4; ++i) {
                int rbase = w * 32 + i * 8;
                int row = rbase + lr;
                gload16(A16 + (size_t)(m0 + row) * K + kt + ((sl ^ (row & 7)) << 3),
                        As16 + rbase * 64);
            }
        }
        {
            int lr = lane >> 3, sl = lane & 7;
            #pragma unroll
            for (int i = 0; i < 4; ++i) {
                int rbase = w * 32 + i * 8;
                int row = rbase + lr;
                gload16(BT + (size_t)(n0 + row) * K + kt + ((sl ^ (row & 7)) << 3),
                        &Bs[rbase][0]);
            }
        }
        __syncthreads();   // drains vmcnt -> LDS ready

        #pragma unroll
        for (int s = 0; s < 2; ++s) {
            bf16x8 af[4], bfr[4];
            #pragma unroll
            for (int f = 0; f < 4; ++f) {
                int ar = wm + f * 16 + l16;
                if (AF32) {
                    const float* base = As32 + ar * 64;
                    f32x4 va0 = *(const f32x4*)(base + (((s * 8 + g * 2 + 0) ^ l16) << 2));
                    f32x4 va1 = *(const f32x4*)(base + (((s * 8 + g * 2 + 1) ^ l16) << 2));
                    af[f] = bf16x8{ (__bf16)va0[0], (__bf16)va0[1], (__bf16)va0[2], (__bf16)va0[3],
                                    (__bf16)va1[0], (__bf16)va1[1], (__bf16)va1[2], (__bf16)va1[3] };
                } else {
                    af[f] = *(const bf16x8*)(As16 + ar * 64 + ((s * 4 + g) ^ (ar & 7)) * 8);
                }
                int br = wn + f * 16 + l16;
                bfr[f] = *(const bf16x8*)(&Bs[br][((s * 4 + g) ^ (br & 7)) * 8]);
            }
            #pragma unroll
            for (int fa = 0; fa < 4; ++fa)
                #pragma unroll
                for (int fb = 0; fb < 4; ++fb)
                    acc[fa][fb] = __builtin_amdgcn_mfma_f32_16x16x32_bf16(
                        af[fa], bfr[fb], acc[fa][fb], 0, 0, 0);
        }
    }

    // epilogue: C/D layout col = lane&15, row = g*4 + reg
    #pragma unroll
    for (int fa = 0; fa < 4; ++fa) {
        #pragma unroll
        for (int fb = 0; fb < 4; ++fb) {
            int n = n0 + wn + fb * 16 + l16;
            float bn = bias[n];
            float v0 = acc[fa][fb][0] + bn;
            float v1 = acc[fa][fb][1] + bn;
            float v2 = acc[fa][fb][2] + bn;
            float v3 = acc[fa][fb][3] + bn;
            int mbase = m0 + wm + fa * 16 + g * 4;   // 4 consecutive rows
            if (EPI == 0) {
                int which = n / INNERn;
                int rem = n - which * INNERn;
                int hh = rem >> 6, d = rem & 63;
                int bb = mbase >> 10;                // tile never straddles b
                int nn = mbase & 1023;
                size_t bh = (size_t)bb * Hn + hh;
                if (which == 2) {
                    // V^T with intra-64 j-permutation (see header comment)
                    int nn0 = nn & ~63;
                    int u = nn & 63;
                    int p = (u & 32) + (((u & 15) >> 2) << 3) + (((u >> 4) & 1) << 2);
                    bf16x4 o = { (__bf16)v0, (__bf16)v1, (__bf16)v2, (__bf16)v3 };
                    *(bf16x4*)(vt + (bh * 64 + d) * Nn + nn0 + p) = o;
                } else {
                    float sc = (which == 0) ? QSCL : 1.0f;
                    __bf16* dst = (which == 0) ? qb : kb;
                    size_t base = ((bh * Nn + nn) << 6) + d;
                    dst[base]       = (__bf16)(v0 * sc);
                    dst[base + 64]  = (__bf16)(v1 * sc);
                    dst[base + 128] = (__bf16)(v2 * sc);
                    dst[base + 192] = (__bf16)(v3 * sc);
                }
            } else {
                outp[(size_t)(mbase + 0) * INNERn + n] = v0;
                outp[(size_t)(mbase + 1) * INNERn + n] = v1;
                outp[(size_t)(mbase + 2) * INNERn + n] = v2;
                outp[(size_t)(mbase + 3) * INNERn + n] = v3;
            }
        }
    }
}

// ---------------------------------------------------------------------------
// Fused attention (R14 form — best measured, 112.9 us total; R15's setprio +
// split-stage regressed attn ~41 -> 51 us and is reverted: setprio hurts
// barrier-synced multi-wave blocks, the m190 regime, not m191's).
// 4 waves, 2 q-tiles per block. 2-phase LDS pipeline, STATIC softmax (exp2,
// log2e pre-folded into Q). l via MFMA-with-ones. V stored j-permuted ->
// single b128 V-read. 1D grid, XCD-aware: bid = qt*96 + bh. [T1]
// ---------------------------------------------------------------------------
__global__ __launch_bounds__(256) void attn_mfma_kernel(
    const __bf16* __restrict__ qb, const __bf16* __restrict__ kb,
    const __bf16* __restrict__ vT, const float* __restrict__ hs,
    __bf16* __restrict__ ao)
{
    __shared__ __attribute__((aligned(16))) __bf16 Ks[2][64][64];
    __shared__ __attribute__((aligned(16))) __bf16 Vs[2][64][64];

    const int tid = threadIdx.x;
    const int lane = tid & 63, w = tid >> 6;
    const int g = lane >> 4, l16 = lane & 15;
    const int bid = blockIdx.x;
    const int bh = bid % 96;            // same bh -> same XCD (96 === 0 mod 8)
    const int qt = bid / 96;            // 0..7
    const int b = bh / Hn, h = bh - b * Hn;

    const __bf16* Qp = qb + ((size_t)bh * Nn + qt * 128 + w * 16) * 64;
    const __bf16* Kp = kb + (size_t)bh * Nn * 64;
    const __bf16* Vp = vT + (size_t)bh * 64 * Nn;

    const int srl = lane >> 3;   // 0..7 local row
    const int ssl = lane & 7;    // chunk slot 0..7

    const __bf16 one1 = (__bf16)1.0f;
    const bf16x8 vones = { one1, one1, one1, one1, one1, one1, one1, one1 };

    bf16x8 qf[2][2];
    #pragma unroll
    for (int t = 0; t < 2; ++t)
        #pragma unroll
        for (int s = 0; s < 2; ++s)
            qf[t][s] = *(const bf16x8*)(Qp + t * 64 * 64 + (size_t)l16 * 64 + s * 32 + g * 8);

    f32x4 oacc0[4] = {}, oacc1[4] = {};
    f32x4 lacc0 = {}, lacc1 = {};

    #pragma unroll
    for (int i = 0; i < 2; ++i) {
        int row = w * 16 + i * 8 + srl;
        gload16(Kp + (size_t)row * 64 + ((ssl ^ (row & 7)) << 3),
                &Ks[0][w * 16 + i * 8][0]);
        gload16(Vp + (size_t)row * Nn + ((ssl ^ (row & 7)) << 3),
                &Vs[0][w * 16 + i * 8][0]);
    }
    __syncthreads();

    int cur = 0;
    for (int jt = 0; jt < Nn / 64; ++jt) {
        if (jt < Nn / 64 - 1) {
            const __bf16* kbase = Kp + (size_t)(jt + 1) * 64 * 64;
            const __bf16* vbase = Vp + (size_t)(jt + 1) * 64;
            #pragma unroll
            for (int i = 0; i < 2; ++i) {
                int row = w * 16 + i * 8 + srl;
                gload16(kbase + (size_t)row * 64 + ((ssl ^ (row & 7)) << 3),
                        &Ks[cur ^ 1][w * 16 + i * 8][0]);
                gload16(vbase + (size_t)row * Nn + ((ssl ^ (row & 7)) << 3),
                        &Vs[cur ^ 1][w * 16 + i * 8][0]);
            }
        }

        // ---- S^T for both q-tiles ----
        f32x4 st0[4] = {}, st1[4] = {};
        #pragma unroll
        for (int s = 0; s < 2; ++s) {
            #pragma unroll
            for (int jf = 0; jf < 4; ++jf) {
                bf16x8 kf = *(const bf16x8*)(
                    &Ks[cur][jf * 16 + l16][((s * 4 + g) ^ (l16 & 7)) * 8]);
                st0[jf] = __builtin_amdgcn_mfma_f32_16x16x32_bf16(kf, qf[0][s], st0[jf], 0, 0, 0);
                st1[jf] = __builtin_amdgcn_mfma_f32_16x16x32_bf16(kf, qf[1][s], st1[jf], 0, 0, 0);
            }
        }

        // ---- static softmax: P = exp2(S') ----
        #pragma unroll
        for (int f = 0; f < 4; ++f)
            #pragma unroll
            for (int r = 0; r < 4; ++r) {
                st0[f][r] = fexp2(st0[f][r]);
                st1[f][r] = fexp2(st1[f][r]);
            }

        // ---- pack P into A-operand fragments ----
        bf16x8 pa0[2], pa1[2];
        #pragma unroll
        for (int s = 0; s < 2; ++s) {
            pa0[s] = bf16x8{ (__bf16)st0[2*s][0], (__bf16)st0[2*s][1],
                             (__bf16)st0[2*s][2], (__bf16)st0[2*s][3],
                             (__bf16)st0[2*s+1][0], (__bf16)st0[2*s+1][1],
                             (__bf16)st0[2*s+1][2], (__bf16)st0[2*s+1][3] };
            pa1[s] = bf16x8{ (__bf16)st1[2*s][0], (__bf16)st1[2*s][1],
                             (__bf16)st1[2*s][2], (__bf16)st1[2*s][3],
                             (__bf16)st1[2*s+1][0], (__bf16)st1[2*s+1][1],
                             (__bf16)st1[2*s+1][2], (__bf16)st1[2*s+1][3] };
        }

        // ---- O += P @ V (single b128 V-read); l += P @ ones ----
        #pragma unroll
        for (int s = 0; s < 2; ++s) {
            lacc0 = __builtin_amdgcn_mfma_f32_16x16x32_bf16(pa0[s], vones, lacc0, 0, 0, 0);
            lacc1 = __builtin_amdgcn_mfma_f32_16x16x32_bf16(pa1[s], vones, lacc1, 0, 0, 0);
            #pragma unroll
            for (int df = 0; df < 4; ++df) {
                bf16x8 bv = *(const bf16x8*)(
                    &Vs[cur][df * 16 + l16][((s * 4 + g) ^ (l16 & 7)) * 8]);
                oacc0[df] = __builtin_amdgcn_mfma_f32_16x16x32_bf16(pa0[s], bv, oacc0[df], 0, 0, 0);
                oacc1[df] = __builtin_amdgcn_mfma_f32_16x16x32_bf16(pa1[s], bv, oacc1[df], 0, 0, 0);
            }
        }

        __syncthreads();
        cur ^= 1;
    }

    // ---- epilogue: linv per row directly from lacc (no shuffles) ----
    const float hscale = hs[h];
    #pragma unroll
    for (int reg = 0; reg < 4; ++reg) {
        float li0 = hscale / lacc0[reg];
        float li1 = hscale / lacc1[reg];
        int q0 = qt * 128 + w * 16 + g * 4 + reg;
        #pragma unroll
        for (int df = 0; df < 4; ++df) {
            ao[((size_t)b * Nn + q0) * INNERn + h * 64 + df * 16 + l16] =
                (__bf16)(oacc0[df][reg] * li0);
            ao[((size_t)b * Nn + q0 + 64) * INNERn + h * 64 + df * 16 + l16] =
                (__bf16)(oacc1[df][reg] * li1);
        }
    }
}

// ---------------------------------------------------------------------------
extern "C" void kernel_launch(void* const* d_in, const int* in_sizes, int n_in,
                              void* d_out, int out_size, void* d_ws, size_t ws_size,
                              hipStream_t stream)
{
    const float* x    = (const float*)d_in[0];
    const float* wqkv = (const float*)d_in[1];
    const float* bqkv = (const float*)d_in[2];
    const float* rw   = (const float*)d_in[3];
    const float* wout = (const float*)d_in[4];
    const float* bout = (const float*)d_in[5];
    float* out = (float*)d_out;
    (void)in_sizes; (void)n_in; (void)out_size; (void)ws_size;

    char* ws = (char*)d_ws;
    size_t off = 0;
    auto alloc = [&](size_t bytes) -> char* {
        char* p = ws + off; off += (bytes + 255) & ~(size_t)255; return p;
    };
    const size_t tsz = (size_t)Mrows * INNERn;          // 6.29M elems
    float*  hsb   = (float*) alloc(Hn * 4);
    __bf16* wqkvT = (__bf16*)alloc((size_t)QKVCOLS * DIMn * 2);
    __bf16* woutT = (__bf16*)alloc((size_t)INNERn * DIMn * 2);
    __bf16* qbuf  = (__bf16*)alloc(tsz * 2);
    __bf16* kbuf  = (__bf16*)alloc(tsz * 2);
    __bf16* vTb   = (__bf16*)alloc(tsz * 2);
    __bf16* aob   = (__bf16*)alloc(tsz * 2);

    prep_kernel<<<dim3(60, 12), dim3(256), 0, stream>>>(
        wqkv, wout, rw, wqkvT, woutT, hsb);

    gemm_bf16_kernel<0, 1><<<dim3((QKVCOLS / 128) * (Mrows / 128)), dim3(256), 0, stream>>>(
        x, wqkvT, bqkv, qbuf, kbuf, vTb, nullptr);

    attn_mfma_kernel<<<dim3((Nn / 128) * Bn * Hn), dim3(256), 0, stream>>>(
        qbuf, kbuf, vTb, hsb, aob);

    gemm_bf16_kernel<1, 0><<<dim3((INNERn / 128) * (Mrows / 128)), dim3(256), 0, stream>>>(
        aob, woutT, bout, nullptr, nullptr, nullptr, out);
}